// Round 9
// baseline (270.898 us; speedup 1.0000x reference)
//
#include <hip/hip_runtime.h>
#include <stdint.h>
#include <stddef.h>

// Problem dims (fixed)
#define TT 2048
#define NH 16
#define HD 64
#define CM 1024            // d_model
#define QSCALE 0.1803368801f   // 0.125 * log2(e): softmax done in exp2 domain
#define PPAD 72

typedef float f32x4  __attribute__((ext_vector_type(4)));
typedef short bf16x8 __attribute__((ext_vector_type(8)));

static __device__ __forceinline__ unsigned short f32_to_bf16(float f) {
    union { float f; unsigned u; } c; c.f = f;
    unsigned u = c.u;
    u += 0x7FFFu + ((u >> 16) & 1u);   // RNE
    return (unsigned short)(u >> 16);
}

// pack high-16s of two floats (truncation) into one u32: [hi|lo]
static __device__ __forceinline__ unsigned pack_bf16_trunc(float lo, float hi) {
    return __builtin_amdgcn_perm(__float_as_uint(hi), __float_as_uint(lo), 0x07060302u);
}

// async global->LDS, 16B per lane. LDS dest = wave-uniform base + lane*16.
static __device__ __forceinline__ void glds16(const unsigned short* g, unsigned short* l) {
    __builtin_amdgcn_global_load_lds(
        (const __attribute__((address_space(1))) unsigned int*)g,
        (__attribute__((address_space(3))) unsigned int*)l,
        16, 0, 0);
}

// HARDENED barrier (drain) — epilogues only.
static __device__ __forceinline__ void hard_barrier() {
    asm volatile("s_waitcnt vmcnt(0) lgkmcnt(0)" ::: "memory");
    __syncthreads();
}

// ---------------------------------------------------------------- casts
// float4-unit ranges: x 2097152 | qkv_w 786432 | out_w 262144
__global__ __launch_bounds__(256) void cast_all(
    const float* __restrict__ x, const float* __restrict__ w1,
    const float* __restrict__ w2,
    unsigned short* __restrict__ X16, unsigned short* __restrict__ W1o,
    unsigned short* __restrict__ W2o) {
    int i = blockIdx.x * blockDim.x + threadIdx.x;
    const float* src; unsigned short* dst; int j;
    if (i < 2097152)      { src = x;  dst = X16; j = i; }
    else if (i < 2883584) { src = w1; dst = W1o; j = i - 2097152; }
    else                  { src = w2; dst = W2o; j = i - 2883584; }
    float4 v = ((const float4*)src)[j];
    ushort4 o;
    o.x = f32_to_bf16(v.x); o.y = f32_to_bf16(v.y);
    o.z = f32_to_bf16(v.z); o.w = f32_to_bf16(v.w);
    ((ushort4*)dst)[j] = o;
}

// ---------------------------------------------------------------- GEMM core (2-phase, kept for gemm_out)
// 256x128 tile, 4 waves of 128x64. BK=32, dbuf 48KB LDS, counted vmcnt(6).
template<bool SWAP>
__device__ __forceinline__ void gemm256_core(
    const unsigned short* __restrict__ A,
    const unsigned short* __restrict__ Bm,
    int m0, int n0,
    unsigned short* lds,
    f32x4 acc[8][4])
{
    const int tid  = threadIdx.x;
    const int lane = tid & 63;
    const int w    = tid >> 6;
    const int l15  = lane & 15;
    const int quad = lane >> 4;
    const int wm   = (w >> 1) * 128;
    const int wn   = (w & 1) * 64;
    const int ro   = (quad ^ (l15 & 3)) * 8;   // read-side swizzle

    const int rr = tid >> 2;
    const int ch = (tid & 3) ^ (rr & 3);
    const unsigned short* gA = A  + (size_t)(m0 + rr) * CM + ch * 8;
    const unsigned short* gB = Bm + (size_t)(n0 + rr) * CM + ch * 8;
    const int wb = (tid & ~63) * 8;            // wave-uniform dest base

    unsigned short* ldsA = lds;                // 2 x 8192 shorts
    unsigned short* ldsB = lds + 16384;        // 2 x 4096 shorts

#define STAGE6(bb)                                                    \
    {                                                                 \
        unsigned short* dA = ldsA + (bb) * 8192 + wb;                 \
        unsigned short* dB = ldsB + (bb) * 4096 + wb;                 \
        glds16(gA,            dA);                                    \
        glds16(gA +  64 * CM, dA + 2048);                             \
        glds16(gA + 128 * CM, dA + 4096);                             \
        glds16(gA + 192 * CM, dA + 6144);                             \
        glds16(gB,            dB);                                    \
        glds16(gB +  64 * CM, dB + 2048);                             \
        gA += 32; gB += 32;                                           \
    }

    STAGE6(0);
    STAGE6(1);

    for (int t = 0; t < 32; ++t) {
        if (t > 0) {
            asm volatile("s_waitcnt lgkmcnt(0)" ::: "memory");
            __builtin_amdgcn_s_barrier();
            asm volatile("" ::: "memory");
            if (t + 1 < 32) STAGE6((t + 1) & 1);
        }
        if (t + 1 < 32) asm volatile("s_waitcnt vmcnt(6)" ::: "memory");
        else            asm volatile("s_waitcnt vmcnt(0)" ::: "memory");
        __builtin_amdgcn_s_barrier();
        asm volatile("" ::: "memory");

        const unsigned short* tA = ldsA + (t & 1) * 8192;
        const unsigned short* tB = ldsB + (t & 1) * 4096;

        bf16x8 bfr[4];
        #pragma unroll
        for (int ni = 0; ni < 4; ++ni)
            bfr[ni] = *(const bf16x8*)(tB + (wn + ni * 16 + l15) * 32 + ro);
        bf16x8 af[8];
        #pragma unroll
        for (int mi = 0; mi < 8; ++mi)
            af[mi] = *(const bf16x8*)(tA + (wm + mi * 16 + l15) * 32 + ro);

        #pragma unroll
        for (int mi = 0; mi < 8; ++mi)
            #pragma unroll
            for (int ni = 0; ni < 4; ++ni)
                acc[mi][ni] = SWAP
                    ? __builtin_amdgcn_mfma_f32_16x16x32_bf16(bfr[ni], af[mi], acc[mi][ni], 0, 0, 0)
                    : __builtin_amdgcn_mfma_f32_16x16x32_bf16(af[mi], bfr[ni], acc[mi][ni], 0, 0, 0);
    }
#undef STAGE6
}

// ---------------------------------------------------------------- 8-phase core
// 256x256 tile, 512 threads = 8 waves (2M x 4N), per-wave 128x64 output.
// 4 K-buffers of BK=32 (A[256][32] + B[256][32], 16KB each) = 128KB LDS.
// Stage tile T+3 during tile T (2 glds/thread spread over 2 phases); boundary
// wait vmcnt(8) retires exactly tile T's 4 staging instrs (T+1,T+2 in
// flight — never drains). 2 phases per K-tile:
//   {stage half of T+3; ds_read frags; lgkm0; setprio(1); 16 MFMA;
//    setprio(0); barrier}
// Same chunk-XOR swizzle as gemm256_core. WAR: buf (T+3)&3 == (T-1)&3; all
// waves' reads of T-1 drained (lgkm0 before its MFMAs) before its phase-B
// barrier, which precedes T's phases.
template<bool SWAP>
__device__ __forceinline__ void gemm8p_core(
    const unsigned short* __restrict__ A,
    const unsigned short* __restrict__ Bm,
    int m0, int n0,
    unsigned short* lds,            // 65536 shorts (128KB)
    f32x4 acc[8][4])
{
    const int tid  = threadIdx.x;
    const int lane = tid & 63;
    const int w    = tid >> 6;          // 0..7
    const int l15  = lane & 15;
    const int quad = lane >> 4;
    const int wm   = (w >> 2) * 128;    // wr*128
    const int wn   = (w & 3) * 64;      // wc*64
    const int ro   = (quad ^ (l15 & 3)) * 8;

    unsigned short* ldsA = lds;             // [4][8192]
    unsigned short* ldsB = lds + 32768;     // [4][8192]

    // staging: 1024 slots (4/row x 256 rows); thread covers c1=tid, c2=tid+512
    const int c1 = tid, c2 = tid + 512;
    const int r1 = c1 >> 2, s1 = ((c1 & 3) ^ (r1 & 3)) * 8;
    const int r2 = c2 >> 2, s2 = ((c2 & 3) ^ (r2 & 3)) * 8;
    const unsigned short* gA1 = A  + (size_t)(m0 + r1) * CM + s1;
    const unsigned short* gA2 = A  + (size_t)(m0 + r2) * CM + s2;
    const unsigned short* gB1 = Bm + (size_t)(n0 + r1) * CM + s1;
    const unsigned short* gB2 = Bm + (size_t)(n0 + r2) * CM + s2;
    unsigned short* dA1 = ldsA + (c1 & ~63) * 8;   // wave-uniform + lane*16B
    unsigned short* dA2 = ldsA + (c2 & ~63) * 8;
    unsigned short* dB1 = ldsB + (c1 & ~63) * 8;
    unsigned short* dB2 = ldsB + (c2 & ~63) * 8;

#define STAGE_H8(T, half)                                             \
    {                                                                 \
        const int bo = ((T) & 3) * 8192;                              \
        const int ko = (T) * 32;                                      \
        if ((half) == 0) {                                            \
            glds16(gA1 + ko, dA1 + bo);                               \
            glds16(gB1 + ko, dB1 + bo);                               \
        } else {                                                      \
            glds16(gA2 + ko, dA2 + bo);                               \
            glds16(gB2 + ko, dB2 + bo);                               \
        }                                                             \
    }
#define STAGE_T8(T) { STAGE_H8(T, 0); STAGE_H8(T, 1); }

    STAGE_T8(0); STAGE_T8(1); STAGE_T8(2);      // 12 instrs in flight

    for (int T = 0; T < 32; ++T) {
        // boundary: retire tile T (4 oldest), keep T+1/T+2 in flight
        if (T <= 29)      asm volatile("s_waitcnt vmcnt(8)" ::: "memory");
        else if (T == 30) asm volatile("s_waitcnt vmcnt(4)" ::: "memory");
        else              asm volatile("s_waitcnt vmcnt(0)" ::: "memory");
        __builtin_amdgcn_s_barrier();
        asm volatile("" ::: "memory");

        const unsigned short* tA = ldsA + (T & 3) * 8192;
        const unsigned short* tB = ldsB + (T & 3) * 8192;

        // ---- phase A: stage half0 of T+3; read A[0..3]+B[0..3]; 16 MFMA
        if (T + 3 < 32) STAGE_H8(T + 3, 0);
        bf16x8 bfr[4], af[4];
        #pragma unroll
        for (int ni = 0; ni < 4; ++ni)
            bfr[ni] = *(const bf16x8*)(tB + (wn + ni * 16 + l15) * 32 + ro);
        #pragma unroll
        for (int mi = 0; mi < 4; ++mi)
            af[mi] = *(const bf16x8*)(tA + (wm + mi * 16 + l15) * 32 + ro);
        asm volatile("s_waitcnt lgkmcnt(0)" ::: "memory");
        __builtin_amdgcn_s_setprio(1);
        #pragma unroll
        for (int mi = 0; mi < 4; ++mi)
            #pragma unroll
            for (int ni = 0; ni < 4; ++ni)
                acc[mi][ni] = SWAP
                    ? __builtin_amdgcn_mfma_f32_16x16x32_bf16(bfr[ni], af[mi], acc[mi][ni], 0, 0, 0)
                    : __builtin_amdgcn_mfma_f32_16x16x32_bf16(af[mi], bfr[ni], acc[mi][ni], 0, 0, 0);
        __builtin_amdgcn_s_setprio(0);
        __builtin_amdgcn_s_barrier();
        asm volatile("" ::: "memory");

        // ---- phase B: stage half1 of T+3; read A[4..7]; 16 MFMA (B reused)
        if (T + 3 < 32) STAGE_H8(T + 3, 1);
        bf16x8 af2[4];
        #pragma unroll
        for (int mi = 0; mi < 4; ++mi)
            af2[mi] = *(const bf16x8*)(tA + (wm + 64 + mi * 16 + l15) * 32 + ro);
        asm volatile("s_waitcnt lgkmcnt(0)" ::: "memory");
        __builtin_amdgcn_s_setprio(1);
        #pragma unroll
        for (int mi = 0; mi < 4; ++mi)
            #pragma unroll
            for (int ni = 0; ni < 4; ++ni)
                acc[4 + mi][ni] = SWAP
                    ? __builtin_amdgcn_mfma_f32_16x16x32_bf16(bfr[ni], af2[mi], acc[4 + mi][ni], 0, 0, 0)
                    : __builtin_amdgcn_mfma_f32_16x16x32_bf16(af2[mi], bfr[ni], acc[4 + mi][ni], 0, 0, 0);
        __builtin_amdgcn_s_setprio(0);
        __builtin_amdgcn_s_barrier();
        asm volatile("" ::: "memory");
    }
#undef STAGE_T8
#undef STAGE_H8
}

// ---------------------------------------------------------------- QKV GEMM (8-phase, 512 threads)
__global__ __launch_bounds__(512, 2) void gemm_qkv(
    const unsigned short* __restrict__ X,
    const unsigned short* __restrict__ W,
    const float* __restrict__ bias,
    unsigned short* __restrict__ Qb,
    unsigned short* __restrict__ Kb,
    unsigned short* __restrict__ Vt)
{
    __shared__ __align__(16) unsigned short lds[65536];   // 128KB
    const int m0 = blockIdx.y * 256;
    const int n0 = blockIdx.x * 256;

    f32x4 acc[8][4];
    f32x4 z = {0.f, 0.f, 0.f, 0.f};
    #pragma unroll
    for (int mi = 0; mi < 8; ++mi)
        #pragma unroll
        for (int ni = 0; ni < 4; ++ni) acc[mi][ni] = z;

    const int region = n0 >> 10;            // 0=Q 1=K 2=V
    if (region < 2) gemm8p_core<true >(X, W, m0, n0, lds, acc);
    else            gemm8p_core<false>(X, W, m0, n0, lds, acc);

    const int tid  = threadIdx.x;
    const int lane = tid & 63;
    const int w    = tid >> 6;
    const int wm   = (w >> 2) * 128;
    const int wn   = (w & 3) * 64;
    const int l15  = lane & 15;
    const int quad = lane >> 4;
    const int b_idx = m0 >> 11;
    const int t0 = m0 & 2047;

    if (region == 2) {
        // V: transpose through LDS in two m-halves, store rows of V^T[d][t]
        hard_barrier();
        #pragma unroll
        for (int half = 0; half < 2; ++half) {
            if ((w >> 2) == half) {
                #pragma unroll
                for (int ni = 0; ni < 4; ++ni) {
                    const int nloc = wn + ni * 16 + l15;        // 0..255
                    const float bv = bias[n0 + nloc];
                    #pragma unroll
                    for (int mi = 0; mi < 8; ++mi) {
                        uint2 pk;
                        pk.x = (unsigned)f32_to_bf16(acc[mi][ni][0] + bv) |
                               ((unsigned)f32_to_bf16(acc[mi][ni][1] + bv) << 16);
                        pk.y = (unsigned)f32_to_bf16(acc[mi][ni][2] + bv) |
                               ((unsigned)f32_to_bf16(acc[mi][ni][3] + bv) << 16);
                        *(uint2*)(lds + nloc * 132 + mi * 16 + quad * 4) = pk;
                    }
                }
            }
            hard_barrier();
            {
                const int row = tid >> 1, seg = tid & 1;        // 256 rows x 2 segs
                const int oin = (n0 & 1023) + row;
                const int hh  = oin >> 6, d = oin & 63;
                unsigned short* dst = Vt + ((size_t)((b_idx << 4) + hh) * HD + d) * TT
                                        + t0 + half * 128 + seg * 64;
                const unsigned short* src = lds + row * 132 + seg * 64;
                #pragma unroll
                for (int u = 0; u < 8; ++u)
                    *(uint4*)(dst + u * 8) = *(const uint4*)(src + u * 8);
            }
            hard_barrier();
        }
        return;
    }

    // Q/K swapped epilogue: col(l15) = t, rows = o; 8B stores of 4 d's
    unsigned short* dst0 = region ? Kb : Qb;
    const float scl = region ? 1.0f : QSCALE;
    #pragma unroll
    for (int mi = 0; mi < 8; ++mi) {
        const int gm = m0 + wm + mi * 16 + l15;
        const int t  = gm & 2047;
        #pragma unroll
        for (int ni = 0; ni < 4; ++ni) {
            const int o  = n0 + wn + ni * 16 + quad * 4;
            const float4 bv = *(const float4*)(bias + o);
            const int oin = o & 1023;
            const int hh = oin >> 6, d = oin & 63;
            const int bh = (b_idx << 4) + hh;
            const float v0 = (acc[mi][ni][0] + bv.x) * scl;
            const float v1 = (acc[mi][ni][1] + bv.y) * scl;
            const float v2 = (acc[mi][ni][2] + bv.z) * scl;
            const float v3 = (acc[mi][ni][3] + bv.w) * scl;
            uint2 pk;
            pk.x = (unsigned)f32_to_bf16(v0) | ((unsigned)f32_to_bf16(v1) << 16);
            pk.y = (unsigned)f32_to_bf16(v2) | ((unsigned)f32_to_bf16(v3) << 16);
            *(uint2*)(dst0 + (((size_t)(bh * TT + t)) << 6) + d) = pk;
        }
    }
}

// ---------------------------------------------------------------- attention
// R8-verified: triple-buffered K/V + counted vmcnt, P via per-wave LDS
// buffer, V frags cached in regs, T5 setprio around MFMA clusters (+3us).
__global__ __launch_bounds__(256, 2) void attn_kernel(
    const unsigned short* __restrict__ Qb,
    const unsigned short* __restrict__ Kb,
    const unsigned short* __restrict__ Vt,
    unsigned short* __restrict__ CTX)
{
    __shared__ __align__(16) unsigned short Kl[3][4096];   // 24KB
    __shared__ __align__(16) unsigned short Vl[3][4096];   // 24KB
    __shared__ __align__(16) unsigned short Pl[4][16 * PPAD]; // 9.2KB

    const int id = blockIdx.x;
    const int qt = 15 - (id >> 6);         // heavy-first
    const int bh = id & 63;
    const int b  = bh >> 4, h = bh & 15;
    const int tid  = threadIdx.x;
    const int lane = tid & 63;
    const int w    = tid >> 6;
    const int l15  = lane & 15;
    const int quad = lane >> 4;
    const int sw   = l15 & 7;              // read-side swizzle key
    const int bhh  = b * NH + h;

    const unsigned short* Kbase = Kb + (size_t)bhh * TT * HD;  // [t][d]
    const unsigned short* Vbase = Vt + (size_t)bhh * HD * TT;  // [d][t]
    const f32x4 z = {0.f, 0.f, 0.f, 0.f};

    const int c1 = tid, c2 = tid + 256;
    const int row1 = c1 >> 3, col1 = ((c1 & 7) ^ (row1 & 7)) * 8;
    const int row2 = c2 >> 3, col2 = ((c2 & 7) ^ (row2 & 7)) * 8;
    unsigned short* dK1 = &Kl[0][(c1 & ~63) * 8];
    unsigned short* dK2 = &Kl[0][(c2 & ~63) * 8];
    unsigned short* dV1 = &Vl[0][(c1 & ~63) * 8];
    unsigned short* dV2 = &Vl[0][(c2 & ~63) * 8];

    const int len = 2 * qt + 2;            // tiles 0..len-1
    const int qb0 = qt * 128;

    const unsigned short* kp1 = Kbase + (size_t)row1 * HD + col1;
    const unsigned short* kp2 = Kbase + (size_t)row2 * HD + col2;
    const unsigned short* vp1 = Vbase + (size_t)row1 * TT + col1;
    const unsigned short* vp2 = Vbase + (size_t)row2 * TT + col2;

    bf16x8 qf[2][2];
    #pragma unroll
    for (int f = 0; f < 2; ++f) {
        const unsigned short* qr =
            Qb + (size_t)(bhh * TT + qb0 + f * 64 + w * 16 + l15) * HD + quad * 8;
        qf[f][0] = *(const bf16x8*)(qr);
        qf[f][1] = *(const bf16x8*)(qr + 32);
    }

    f32x4 o_acc[2][4];
    #pragma unroll
    for (int f = 0; f < 2; ++f)
        #pragma unroll
        for (int di = 0; di < 4; ++di) o_acc[f][di] = z;
    float lrun[2] = {0.f, 0.f};

    // prologue: stage tiles 0,1,(2)
#define STAGE_KV(bufidx)                                               \
    {                                                                  \
        const int nx = (bufidx) * 4096;                                \
        glds16(kp1, dK1 + nx); glds16(kp2, dK2 + nx);                  \
        glds16(vp1, dV1 + nx); glds16(vp2, dV2 + nx);                  \
        kp1 += 64 * HD; kp2 += 64 * HD; vp1 += 64; vp2 += 64;          \
    }
    STAGE_KV(0);
    STAGE_KV(1);
    if (len > 2) STAGE_KV(2);

    for (int i = 0; i < len; ++i) {
        const int cur = i % 3;
        if (i > 0) {
            asm volatile("s_waitcnt lgkmcnt(0)" ::: "memory"); // my reads of retiring buf done
            __builtin_amdgcn_s_barrier();                      // all waves done -> WAR safe
            asm volatile("" ::: "memory");
            if (i + 2 < len) STAGE_KV((i + 2) % 3);
        }
        // retire exactly tile i's 4 loads; keep i+1/i+2 in flight
        if (i + 2 < len)      asm volatile("s_waitcnt vmcnt(8)" ::: "memory");
        else if (i + 1 < len) asm volatile("s_waitcnt vmcnt(4)" ::: "memory");
        else                  asm volatile("s_waitcnt vmcnt(0)" ::: "memory");
        __builtin_amdgcn_s_barrier();                          // tile i visible to all
        asm volatile("" ::: "memory");

        const unsigned short* Kt    = &Kl[0][0] + cur * 4096;
        const unsigned short* Vtile = &Vl[0][0] + cur * 4096;
        const bool f0act = (i < len - 1);

        f32x4 s0[4], s1[4];
        __builtin_amdgcn_s_setprio(1);
        #pragma unroll
        for (int ni = 0; ni < 4; ++ni) {
            const unsigned short* kr = Kt + (ni * 16 + l15) * 64;
            bf16x8 kf0 = *(const bf16x8*)(kr + ((quad ^ sw) * 8));
            bf16x8 kf1 = *(const bf16x8*)(kr + (((quad + 4) ^ sw) * 8));
            if (f0act) {
                f32x4 a = __builtin_amdgcn_mfma_f32_16x16x32_bf16(kf0, qf[0][0], z, 0, 0, 0);
                s0[ni] = __builtin_amdgcn_mfma_f32_16x16x32_bf16(kf1, qf[0][1], a, 0, 0, 0);
            }
            f32x4 a1 = __builtin_amdgcn_mfma_f32_16x16x32_bf16(kf0, qf[1][0], z, 0, 0, 0);
            s1[ni] = __builtin_amdgcn_mfma_f32_16x16x32_bf16(kf1, qf[1][1], a1, 0, 0, 0);
        }
        __builtin_amdgcn_s_setprio(0);

        const int qloc = w * 16 + l15;
        if (f0act && i == len - 2) {
            #pragma unroll
            for (int ni = 0; ni < 4; ++ni)
                #pragma unroll
                for (int r = 0; r < 4; ++r)
                    if (ni * 16 + quad * 4 + r > qloc) s0[ni][r] = -1e30f;
        }
        if (i == len - 1) {
            #pragma unroll
            for (int ni = 0; ni < 4; ++ni)
                #pragma unroll
                for (int r = 0; r < 4; ++r)
                    if (ni * 16 + quad * 4 + r > qloc) s1[ni][r] = -1e30f;
        }

        // tree-reduced sum; P -> single per-wave buffer Pl[w]
        #define SOFTMAX_P(S, F)                                              \
        {                                                                    \
            float tni[4];                                                    \
            _Pragma("unroll")                                                \
            for (int ni = 0; ni < 4; ++ni) {                                 \
                float p0 = __builtin_amdgcn_exp2f(S[ni][0]);                 \
                float p1 = __builtin_amdgcn_exp2f(S[ni][1]);                 \
                float p2 = __builtin_amdgcn_exp2f(S[ni][2]);                 \
                float p3 = __builtin_amdgcn_exp2f(S[ni][3]);                 \
                S[ni][0] = p0; S[ni][1] = p1; S[ni][2] = p2; S[ni][3] = p3;  \
                tni[ni] = (p0 + p1) + (p2 + p3);                             \
            }                                                                \
            lrun[F] += (tni[0] + tni[1]) + (tni[2] + tni[3]);                \
            unsigned short* pwf = Pl[w];                                     \
            _Pragma("unroll")                                                \
            for (int ni = 0; ni < 4; ++ni) {                                 \
                uint2 pk;                                                    \
                pk.x = pack_bf16_trunc(S[ni][0], S[ni][1]);                  \
                pk.y = pack_bf16_trunc(S[ni][2], S[ni][3]);                  \
                *(uint2*)(pwf + l15 * PPAD + ni * 16 + quad * 4) = pk;       \
            }                                                                \
        }

        bf16x8 vf[2][4];
        // f1 half (always active): softmax -> P buffer -> PV, cache V frags
        SOFTMAX_P(s1, 1);
        asm volatile("s_waitcnt lgkmcnt(0)" ::: "memory");  // P RAW (same wave)
        __builtin_amdgcn_s_setprio(1);
        #pragma unroll
        for (int c = 0; c < 2; ++c) {
            bf16x8 pf1 = *(const bf16x8*)(Pl[w] + l15 * PPAD + c * 32 + quad * 8);
            #pragma unroll
            for (int di = 0; di < 4; ++di) {
                vf[c][di] = *(const bf16x8*)(Vtile + (di * 16 + l15) * 64
                                           + (((c * 4 + quad) ^ sw) * 8));
                o_acc[1][di] = __builtin_amdgcn_mfma_f32_16x16x32_bf16(vf[c][di], pf1, o_acc[1][di], 0, 0, 0);
            }
        }
        __builtin_amdgcn_s_setprio(0);
        // f0 half: reuse V regs
        if (f0act) {
            SOFTMAX_P(s0, 0);
            asm volatile("s_waitcnt lgkmcnt(0)" ::: "memory");
            __builtin_amdgcn_s_setprio(1);
            #pragma unroll
            for (int c = 0; c < 2; ++c) {
                bf16x8 pf0 = *(const bf16x8*)(Pl[w] + l15 * PPAD + c * 32 + quad * 8);
                #pragma unroll
                for (int di = 0; di < 4; ++di)
                    o_acc[0][di] = __builtin_amdgcn_mfma_f32_16x16x32_bf16(vf[c][di], pf0, o_acc[0][di], 0, 0, 0);
            }
            __builtin_amdgcn_s_setprio(0);
        }
        #undef SOFTMAX_P
    }
#undef STAGE_KV

    #pragma unroll
    for (int f = 0; f < 2; ++f) {
        float lt = lrun[f];
        lt += __shfl_xor(lt, 16);
        lt += __shfl_xor(lt, 32);
        const float inv = 1.0f / lt;
        unsigned short* crow =
            CTX + (size_t)(b * TT + qb0 + f * 64 + w * 16 + l15) * CM + h * HD;
        #pragma unroll
        for (int di = 0; di < 4; ++di) {
            uint2 pk;
            pk.x = (unsigned)f32_to_bf16(o_acc[f][di][0] * inv) |
                   ((unsigned)f32_to_bf16(o_acc[f][di][1] * inv) << 16);
            pk.y = (unsigned)f32_to_bf16(o_acc[f][di][2] * inv) |
                   ((unsigned)f32_to_bf16(o_acc[f][di][3] * inv) << 16);
            *(uint2*)(crow + di * 16 + quad * 4) = pk;
        }
    }
}

// ---------------------------------------------------------------- out proj
__global__ __launch_bounds__(256, 2) void gemm_out(
    const unsigned short* __restrict__ CTX,
    const unsigned short* __restrict__ W,
    const float* __restrict__ bias,
    float* __restrict__ out)
{
    __shared__ __align__(16) unsigned short lds[24576];
    const int m0 = blockIdx.y * 256;
    const int n0 = blockIdx.x * 128;

    f32x4 acc[8][4];
    f32x4 z = {0.f, 0.f, 0.f, 0.f};
    #pragma unroll
    for (int mi = 0; mi < 8; ++mi)
        #pragma unroll
        for (int ni = 0; ni < 4; ++ni) acc[mi][ni] = z;

    gemm256_core<true>(CTX, W, m0, n0, lds, acc);

    const int tid  = threadIdx.x;
    const int lane = tid & 63;
    const int w    = tid >> 6;
    const int wm   = (w >> 1) * 128;
    const int wn   = (w & 1) * 64;
    const int l15  = lane & 15;
    const int quad = lane >> 4;

    #pragma unroll
    for (int mi = 0; mi < 8; ++mi) {
        const int gm = m0 + wm + mi * 16 + l15;
        float* orow = out + (size_t)gm * CM;
        #pragma unroll
        for (int ni = 0; ni < 4; ++ni) {
            const int o = n0 + wn + ni * 16 + quad * 4;
            const float4 bv = *(const float4*)(bias + o);
            float4 v;
            v.x = acc[mi][ni][0] + bv.x;
            v.y = acc[mi][ni][1] + bv.y;
            v.z = acc[mi][ni][2] + bv.z;
            v.w = acc[mi][ni][3] + bv.w;
            *(float4*)(orow + o) = v;
        }
    }
}

// ---------------------------------------------------------------- launch
extern "C" void kernel_launch(void* const* d_in, const int* in_sizes, int n_in,
                              void* d_out, int out_size, void* d_ws, size_t ws_size,
                              hipStream_t stream) {
    const float* x     = (const float*)d_in[0];
    const float* qkv_w = (const float*)d_in[1];
    const float* qkv_b = (const float*)d_in[2];
    const float* out_w = (const float*)d_in[3];
    const float* out_b = (const float*)d_in[4];
    float* out = (float*)d_out;

    char* ws = (char*)d_ws;
    unsigned short* X16 = (unsigned short*)(ws + 0);         // 16 MB
    unsigned short* W1  = (unsigned short*)(ws + 16777216);  // 6 MB
    unsigned short* W2  = (unsigned short*)(ws + 23068672);  // 2 MB
    unsigned short* Qb  = (unsigned short*)(ws + 25165824);  // 16 MB
    unsigned short* Kb  = (unsigned short*)(ws + 41943040);  // 16 MB
    unsigned short* Vt  = (unsigned short*)(ws + 58720256);  // 16 MB
    unsigned short* CTX = (unsigned short*)(ws + 75497472);  // 16 MB  (~92 MB)

    cast_all<<<12288, 256, 0, stream>>>(x, qkv_w, out_w, X16, W1, W2);

    gemm_qkv<<<dim3(12, 32), 512, 0, stream>>>(X16, W1, qkv_b, Qb, Kb, Vt);
    attn_kernel<<<1024, 256, 0, stream>>>(Qb, Kb, Vt, CTX);
    gemm_out<<<dim3(8, 32), 256, 0, stream>>>(CTX, W2, out_b, out);
}

// Round 10
// 249.174 us; speedup vs baseline: 1.0872x; 1.0872x over previous
//
#include <hip/hip_runtime.h>
#include <stdint.h>
#include <stddef.h>

// Problem dims (fixed)
#define TT 2048
#define NH 16
#define HD 64
#define CM 1024            // d_model
#define QSCALE 0.1803368801f   // 0.125 * log2(e): softmax done in exp2 domain
#define PPAD 72

typedef float f32x4  __attribute__((ext_vector_type(4)));
typedef short bf16x8 __attribute__((ext_vector_type(8)));

static __device__ __forceinline__ unsigned short f32_to_bf16(float f) {
    union { float f; unsigned u; } c; c.f = f;
    unsigned u = c.u;
    u += 0x7FFFu + ((u >> 16) & 1u);   // RNE
    return (unsigned short)(u >> 16);
}

// pack high-16s of two floats (truncation) into one u32: [hi|lo]
static __device__ __forceinline__ unsigned pack_bf16_trunc(float lo, float hi) {
    return __builtin_amdgcn_perm(__float_as_uint(hi), __float_as_uint(lo), 0x07060302u);
}

// async global->LDS, 16B per lane. LDS dest = wave-uniform base + lane*16.
static __device__ __forceinline__ void glds16(const unsigned short* g, unsigned short* l) {
    __builtin_amdgcn_global_load_lds(
        (const __attribute__((address_space(1))) unsigned int*)g,
        (__attribute__((address_space(3))) unsigned int*)l,
        16, 0, 0);
}

// HARDENED barrier (drain) — epilogues only.
static __device__ __forceinline__ void hard_barrier() {
    asm volatile("s_waitcnt vmcnt(0) lgkmcnt(0)" ::: "memory");
    __syncthreads();
}

// ---------------------------------------------------------------- casts
// float4-unit ranges: x 2097152 | qkv_w 786432 | out_w 262144
__global__ __launch_bounds__(256) void cast_all(
    const float* __restrict__ x, const float* __restrict__ w1,
    const float* __restrict__ w2,
    unsigned short* __restrict__ X16, unsigned short* __restrict__ W1o,
    unsigned short* __restrict__ W2o) {
    int i = blockIdx.x * blockDim.x + threadIdx.x;
    const float* src; unsigned short* dst; int j;
    if (i < 2097152)      { src = x;  dst = X16; j = i; }
    else if (i < 2883584) { src = w1; dst = W1o; j = i - 2097152; }
    else                  { src = w2; dst = W2o; j = i - 2883584; }
    float4 v = ((const float4*)src)[j];
    ushort4 o;
    o.x = f32_to_bf16(v.x); o.y = f32_to_bf16(v.y);
    o.z = f32_to_bf16(v.z); o.w = f32_to_bf16(v.w);
    ((ushort4*)dst)[j] = o;
}

// ---------------------------------------------------------------- GEMM core (256x128, 2-phase)
// 4 waves of 128x64. BK=32, dbuf 48KB LDS, counted vmcnt(6) — R8-verified.
template<bool SWAP>
__device__ __forceinline__ void gemm256_core(
    const unsigned short* __restrict__ A,
    const unsigned short* __restrict__ Bm,
    int m0, int n0,
    unsigned short* lds,
    f32x4 acc[8][4])
{
    const int tid  = threadIdx.x;
    const int lane = tid & 63;
    const int w    = tid >> 6;
    const int l15  = lane & 15;
    const int quad = lane >> 4;
    const int wm   = (w >> 1) * 128;
    const int wn   = (w & 1) * 64;
    const int ro   = (quad ^ (l15 & 3)) * 8;   // read-side swizzle

    const int rr = tid >> 2;
    const int ch = (tid & 3) ^ (rr & 3);
    const unsigned short* gA = A  + (size_t)(m0 + rr) * CM + ch * 8;
    const unsigned short* gB = Bm + (size_t)(n0 + rr) * CM + ch * 8;
    const int wb = (tid & ~63) * 8;            // wave-uniform dest base

    unsigned short* ldsA = lds;                // 2 x 8192 shorts
    unsigned short* ldsB = lds + 16384;        // 2 x 4096 shorts

#define STAGE6(bb)                                                    \
    {                                                                 \
        unsigned short* dA = ldsA + (bb) * 8192 + wb;                 \
        unsigned short* dB = ldsB + (bb) * 4096 + wb;                 \
        glds16(gA,            dA);                                    \
        glds16(gA +  64 * CM, dA + 2048);                             \
        glds16(gA + 128 * CM, dA + 4096);                             \
        glds16(gA + 192 * CM, dA + 6144);                             \
        glds16(gB,            dB);                                    \
        glds16(gB +  64 * CM, dB + 2048);                             \
        gA += 32; gB += 32;                                           \
    }

    STAGE6(0);
    STAGE6(1);

    for (int t = 0; t < 32; ++t) {
        if (t > 0) {
            asm volatile("s_waitcnt lgkmcnt(0)" ::: "memory");
            __builtin_amdgcn_s_barrier();
            asm volatile("" ::: "memory");
            if (t + 1 < 32) STAGE6((t + 1) & 1);
        }
        if (t + 1 < 32) asm volatile("s_waitcnt vmcnt(6)" ::: "memory");
        else            asm volatile("s_waitcnt vmcnt(0)" ::: "memory");
        __builtin_amdgcn_s_barrier();
        asm volatile("" ::: "memory");

        const unsigned short* tA = ldsA + (t & 1) * 8192;
        const unsigned short* tB = ldsB + (t & 1) * 4096;

        bf16x8 bfr[4];
        #pragma unroll
        for (int ni = 0; ni < 4; ++ni)
            bfr[ni] = *(const bf16x8*)(tB + (wn + ni * 16 + l15) * 32 + ro);
        bf16x8 af[8];
        #pragma unroll
        for (int mi = 0; mi < 8; ++mi)
            af[mi] = *(const bf16x8*)(tA + (wm + mi * 16 + l15) * 32 + ro);

        #pragma unroll
        for (int mi = 0; mi < 8; ++mi)
            #pragma unroll
            for (int ni = 0; ni < 4; ++ni)
                acc[mi][ni] = SWAP
                    ? __builtin_amdgcn_mfma_f32_16x16x32_bf16(bfr[ni], af[mi], acc[mi][ni], 0, 0, 0)
                    : __builtin_amdgcn_mfma_f32_16x16x32_bf16(af[mi], bfr[ni], acc[mi][ni], 0, 0, 0);
    }
#undef STAGE6
}

// ---------------------------------------------------------------- GEMM core (128x128, 2-phase)
// R0-baseline-verified. 4 waves of 64x64; dbuf 32KB; used by gemm_out for
// perfect 512-block packing (2 blocks/CU x 256 CU = one full round).
template<bool SWAP>
__device__ __forceinline__ void gemm_core_dbuf(
    const unsigned short* __restrict__ A,
    const unsigned short* __restrict__ Bm,
    int K, int m0, int n0,
    unsigned short* lds,
    f32x4 acc[4][4])
{
    const int tid  = threadIdx.x;
    const int lane = tid & 63;
    const int wm   = ((tid >> 6) >> 1) * 64;
    const int wn   = ((tid >> 6) & 1) * 64;
    const int l15  = lane & 15;
    const int quad = lane >> 4;
    const int rsw  = l15 & 3;              // read-side swizzle key

    unsigned short* ldsA = lds;
    unsigned short* ldsB = lds + 8192;

    const int c1 = tid, c2 = tid + 256;
    const int r1 = c1 >> 2, s1 = ((c1 & 3) ^ (r1 & 3)) * 8;
    const int r2 = c2 >> 2, s2 = ((c2 & 3) ^ (r2 & 3)) * 8;
    const unsigned short* gA1 = A  + (size_t)(m0 + r1) * K + s1;
    const unsigned short* gA2 = A  + (size_t)(m0 + r2) * K + s2;
    const unsigned short* gB1 = Bm + (size_t)(n0 + r1) * K + s1;
    const unsigned short* gB2 = Bm + (size_t)(n0 + r2) * K + s2;
    unsigned short* dA1 = ldsA + (c1 & ~63) * 8;
    unsigned short* dA2 = ldsA + (c2 & ~63) * 8;
    unsigned short* dB1 = ldsB + (c1 & ~63) * 8;
    unsigned short* dB2 = ldsB + (c2 & ~63) * 8;

    // stage k=0 into buf 0
    glds16(gA1, dA1); glds16(gA2, dA2);
    glds16(gB1, dB1); glds16(gB2, dB2);
    gA1 += 32; gA2 += 32; gB1 += 32; gB2 += 32;

    int step = 0;
    for (int k0 = 0; k0 < K; k0 += 32, step ^= 1) {
        hard_barrier();                     // buf[step] landed; all reads done
        if (k0 + 32 < K) {                  // prefetch next into other buf
            const int nx = (step ^ 1) * 4096;
            glds16(gA1, dA1 + nx); glds16(gA2, dA2 + nx);
            glds16(gB1, dB1 + nx); glds16(gB2, dB2 + nx);
            gA1 += 32; gA2 += 32; gB1 += 32; gB2 += 32;
        }
        const unsigned short* tA = ldsA + step * 4096;
        const unsigned short* tB = ldsB + step * 4096;
        const int ro = (quad ^ rsw) * 8;    // swizzled in-row offset

        bf16x8 af[4], bfr[4];
        #pragma unroll
        for (int mi = 0; mi < 4; ++mi)
            af[mi] = *(const bf16x8*)(tA + (wm + mi * 16 + l15) * 32 + ro);
        #pragma unroll
        for (int ni = 0; ni < 4; ++ni)
            bfr[ni] = *(const bf16x8*)(tB + (wn + ni * 16 + l15) * 32 + ro);

        #pragma unroll
        for (int mi = 0; mi < 4; ++mi)
            #pragma unroll
            for (int ni = 0; ni < 4; ++ni)
                acc[mi][ni] = SWAP
                    ? __builtin_amdgcn_mfma_f32_16x16x32_bf16(bfr[ni], af[mi], acc[mi][ni], 0, 0, 0)
                    : __builtin_amdgcn_mfma_f32_16x16x32_bf16(af[mi], bfr[ni], acc[mi][ni], 0, 0, 0);
    }
}

// ---------------------------------------------------------------- QKV GEMM (R8-verified)
__global__ __launch_bounds__(256, 2) void gemm_qkv(
    const unsigned short* __restrict__ X,
    const unsigned short* __restrict__ W,
    const float* __restrict__ bias,
    unsigned short* __restrict__ Qb,
    unsigned short* __restrict__ Kb,
    unsigned short* __restrict__ Vt)
{
    __shared__ __align__(16) unsigned short lds[24576];   // 48KB
    const int m0 = blockIdx.y * 256;
    const int n0 = blockIdx.x * 128;

    f32x4 acc[8][4];
    f32x4 z = {0.f, 0.f, 0.f, 0.f};
    #pragma unroll
    for (int mi = 0; mi < 8; ++mi)
        #pragma unroll
        for (int ni = 0; ni < 4; ++ni) acc[mi][ni] = z;

    const int region = n0 >> 10;            // 0=Q 1=K 2=V
    if (region < 2) gemm256_core<true >(X, W, m0, n0, lds, acc);
    else            gemm256_core<false>(X, W, m0, n0, lds, acc);

    const int tid  = threadIdx.x;
    const int lane = tid & 63;
    const int w    = tid >> 6;
    const int wm   = (w >> 1) * 128;
    const int wn   = (w & 1) * 64;
    const int l15  = lane & 15;
    const int quad = lane >> 4;
    const int b_idx = m0 >> 11;
    const int t0 = m0 & 2047;

    if (region == 2) {
        // V: transpose through LDS, store coalesced rows of V^T[d][t]
        hard_barrier();
        #pragma unroll
        for (int hn = 0; hn < 2; ++hn) {
            if ((w & 1) == hn) {
                #pragma unroll
                for (int ni = 0; ni < 4; ++ni) {
                    const int nloc = ni * 16 + l15;
                    const float bv = bias[n0 + hn * 64 + nloc];
                    #pragma unroll
                    for (int mi = 0; mi < 8; ++mi) {
                        uint2 pk;
                        pk.x = (unsigned)f32_to_bf16(acc[mi][ni][0] + bv) |
                               ((unsigned)f32_to_bf16(acc[mi][ni][1] + bv) << 16);
                        pk.y = (unsigned)f32_to_bf16(acc[mi][ni][2] + bv) |
                               ((unsigned)f32_to_bf16(acc[mi][ni][3] + bv) << 16);
                        *(uint2*)(lds + nloc * 264 + wm + mi * 16 + quad * 4) = pk;
                    }
                }
            }
            hard_barrier();
            {
                const int row = tid >> 2, seg = tid & 3;
                const int o   = n0 + hn * 64 + row;
                const int oin = o & 1023;
                const int hh  = oin >> 6, d = oin & 63;
                unsigned short* dst = Vt + ((size_t)((b_idx << 4) + hh) * HD + d) * TT
                                        + t0 + seg * 64;
                const unsigned short* src = lds + row * 264 + seg * 64;
                #pragma unroll
                for (int u = 0; u < 8; ++u)
                    *(uint4*)(dst + u * 8) = *(const uint4*)(src + u * 8);
            }
            hard_barrier();
        }
        return;
    }

    // Q/K swapped epilogue: col(l15) = t, rows = o; 8B stores of 4 d's
    unsigned short* dst0 = region ? Kb : Qb;
    const float scl = region ? 1.0f : QSCALE;
    #pragma unroll
    for (int mi = 0; mi < 8; ++mi) {
        const int gm = m0 + wm + mi * 16 + l15;
        const int t  = gm & 2047;
        #pragma unroll
        for (int ni = 0; ni < 4; ++ni) {
            const int o  = n0 + wn + ni * 16 + quad * 4;
            const float4 bv = *(const float4*)(bias + o);
            const int oin = o & 1023;
            const int hh = oin >> 6, d = oin & 63;
            const int bh = (b_idx << 4) + hh;
            const float v0 = (acc[mi][ni][0] + bv.x) * scl;
            const float v1 = (acc[mi][ni][1] + bv.y) * scl;
            const float v2 = (acc[mi][ni][2] + bv.z) * scl;
            const float v3 = (acc[mi][ni][3] + bv.w) * scl;
            uint2 pk;
            pk.x = (unsigned)f32_to_bf16(v0) | ((unsigned)f32_to_bf16(v1) << 16);
            pk.y = (unsigned)f32_to_bf16(v2) | ((unsigned)f32_to_bf16(v3) << 16);
            *(uint2*)(dst0 + (((size_t)(bh * TT + t)) << 6) + d) = pk;
        }
    }
}

// ---------------------------------------------------------------- attention (R8-verified)
// Triple-buffered K/V + counted vmcnt, P via per-wave LDS buffer, V frags
// cached in regs, T5 setprio around MFMA clusters.
__global__ __launch_bounds__(256, 2) void attn_kernel(
    const unsigned short* __restrict__ Qb,
    const unsigned short* __restrict__ Kb,
    const unsigned short* __restrict__ Vt,
    unsigned short* __restrict__ CTX)
{
    __shared__ __align__(16) unsigned short Kl[3][4096];   // 24KB
    __shared__ __align__(16) unsigned short Vl[3][4096];   // 24KB
    __shared__ __align__(16) unsigned short Pl[4][16 * PPAD]; // 9.2KB

    const int id = blockIdx.x;
    const int qt = 15 - (id >> 6);         // heavy-first
    const int bh = id & 63;
    const int b  = bh >> 4, h = bh & 15;
    const int tid  = threadIdx.x;
    const int lane = tid & 63;
    const int w    = tid >> 6;
    const int l15  = lane & 15;
    const int quad = lane >> 4;
    const int sw   = l15 & 7;              // read-side swizzle key
    const int bhh  = b * NH + h;

    const unsigned short* Kbase = Kb + (size_t)bhh * TT * HD;  // [t][d]
    const unsigned short* Vbase = Vt + (size_t)bhh * HD * TT;  // [d][t]
    const f32x4 z = {0.f, 0.f, 0.f, 0.f};

    const int c1 = tid, c2 = tid + 256;
    const int row1 = c1 >> 3, col1 = ((c1 & 7) ^ (row1 & 7)) * 8;
    const int row2 = c2 >> 3, col2 = ((c2 & 7) ^ (row2 & 7)) * 8;
    unsigned short* dK1 = &Kl[0][(c1 & ~63) * 8];
    unsigned short* dK2 = &Kl[0][(c2 & ~63) * 8];
    unsigned short* dV1 = &Vl[0][(c1 & ~63) * 8];
    unsigned short* dV2 = &Vl[0][(c2 & ~63) * 8];

    const int len = 2 * qt + 2;            // tiles 0..len-1
    const int qb0 = qt * 128;

    const unsigned short* kp1 = Kbase + (size_t)row1 * HD + col1;
    const unsigned short* kp2 = Kbase + (size_t)row2 * HD + col2;
    const unsigned short* vp1 = Vbase + (size_t)row1 * TT + col1;
    const unsigned short* vp2 = Vbase + (size_t)row2 * TT + col2;

    bf16x8 qf[2][2];
    #pragma unroll
    for (int f = 0; f < 2; ++f) {
        const unsigned short* qr =
            Qb + (size_t)(bhh * TT + qb0 + f * 64 + w * 16 + l15) * HD + quad * 8;
        qf[f][0] = *(const bf16x8*)(qr);
        qf[f][1] = *(const bf16x8*)(qr + 32);
    }

    f32x4 o_acc[2][4];
    #pragma unroll
    for (int f = 0; f < 2; ++f)
        #pragma unroll
        for (int di = 0; di < 4; ++di) o_acc[f][di] = z;
    float lrun[2] = {0.f, 0.f};

    // prologue: stage tiles 0,1,(2)
#define STAGE_KV(bufidx)                                               \
    {                                                                  \
        const int nx = (bufidx) * 4096;                                \
        glds16(kp1, dK1 + nx); glds16(kp2, dK2 + nx);                  \
        glds16(vp1, dV1 + nx); glds16(vp2, dV2 + nx);                  \
        kp1 += 64 * HD; kp2 += 64 * HD; vp1 += 64; vp2 += 64;          \
    }
    STAGE_KV(0);
    STAGE_KV(1);
    if (len > 2) STAGE_KV(2);

    for (int i = 0; i < len; ++i) {
        const int cur = i % 3;
        if (i > 0) {
            asm volatile("s_waitcnt lgkmcnt(0)" ::: "memory"); // my reads of retiring buf done
            __builtin_amdgcn_s_barrier();                      // all waves done -> WAR safe
            asm volatile("" ::: "memory");
            if (i + 2 < len) STAGE_KV((i + 2) % 3);
        }
        // retire exactly tile i's 4 loads; keep i+1/i+2 in flight
        if (i + 2 < len)      asm volatile("s_waitcnt vmcnt(8)" ::: "memory");
        else if (i + 1 < len) asm volatile("s_waitcnt vmcnt(4)" ::: "memory");
        else                  asm volatile("s_waitcnt vmcnt(0)" ::: "memory");
        __builtin_amdgcn_s_barrier();                          // tile i visible to all
        asm volatile("" ::: "memory");

        const unsigned short* Kt    = &Kl[0][0] + cur * 4096;
        const unsigned short* Vtile = &Vl[0][0] + cur * 4096;
        const bool f0act = (i < len - 1);

        f32x4 s0[4], s1[4];
        __builtin_amdgcn_s_setprio(1);
        #pragma unroll
        for (int ni = 0; ni < 4; ++ni) {
            const unsigned short* kr = Kt + (ni * 16 + l15) * 64;
            bf16x8 kf0 = *(const bf16x8*)(kr + ((quad ^ sw) * 8));
            bf16x8 kf1 = *(const bf16x8*)(kr + (((quad + 4) ^ sw) * 8));
            if (f0act) {
                f32x4 a = __builtin_amdgcn_mfma_f32_16x16x32_bf16(kf0, qf[0][0], z, 0, 0, 0);
                s0[ni] = __builtin_amdgcn_mfma_f32_16x16x32_bf16(kf1, qf[0][1], a, 0, 0, 0);
            }
            f32x4 a1 = __builtin_amdgcn_mfma_f32_16x16x32_bf16(kf0, qf[1][0], z, 0, 0, 0);
            s1[ni] = __builtin_amdgcn_mfma_f32_16x16x32_bf16(kf1, qf[1][1], a1, 0, 0, 0);
        }
        __builtin_amdgcn_s_setprio(0);

        const int qloc = w * 16 + l15;
        if (f0act && i == len - 2) {
            #pragma unroll
            for (int ni = 0; ni < 4; ++ni)
                #pragma unroll
                for (int r = 0; r < 4; ++r)
                    if (ni * 16 + quad * 4 + r > qloc) s0[ni][r] = -1e30f;
        }
        if (i == len - 1) {
            #pragma unroll
            for (int ni = 0; ni < 4; ++ni)
                #pragma unroll
                for (int r = 0; r < 4; ++r)
                    if (ni * 16 + quad * 4 + r > qloc) s1[ni][r] = -1e30f;
        }

        // tree-reduced sum; P -> single per-wave buffer Pl[w]
        #define SOFTMAX_P(S, F)                                              \
        {                                                                    \
            float tni[4];                                                    \
            _Pragma("unroll")                                                \
            for (int ni = 0; ni < 4; ++ni) {                                 \
                float p0 = __builtin_amdgcn_exp2f(S[ni][0]);                 \
                float p1 = __builtin_amdgcn_exp2f(S[ni][1]);                 \
                float p2 = __builtin_amdgcn_exp2f(S[ni][2]);                 \
                float p3 = __builtin_amdgcn_exp2f(S[ni][3]);                 \
                S[ni][0] = p0; S[ni][1] = p1; S[ni][2] = p2; S[ni][3] = p3;  \
                tni[ni] = (p0 + p1) + (p2 + p3);                             \
            }                                                                \
            lrun[F] += (tni[0] + tni[1]) + (tni[2] + tni[3]);                \
            unsigned short* pwf = Pl[w];                                     \
            _Pragma("unroll")                                                \
            for (int ni = 0; ni < 4; ++ni) {                                 \
                uint2 pk;                                                    \
                pk.x = pack_bf16_trunc(S[ni][0], S[ni][1]);                  \
                pk.y = pack_bf16_trunc(S[ni][2], S[ni][3]);                  \
                *(uint2*)(pwf + l15 * PPAD + ni * 16 + quad * 4) = pk;       \
            }                                                                \
        }

        bf16x8 vf[2][4];
        // f1 half (always active): softmax -> P buffer -> PV, cache V frags
        SOFTMAX_P(s1, 1);
        asm volatile("s_waitcnt lgkmcnt(0)" ::: "memory");  // P RAW (same wave)
        __builtin_amdgcn_s_setprio(1);
        #pragma unroll
        for (int c = 0; c < 2; ++c) {
            bf16x8 pf1 = *(const bf16x8*)(Pl[w] + l15 * PPAD + c * 32 + quad * 8);
            #pragma unroll
            for (int di = 0; di < 4; ++di) {
                vf[c][di] = *(const bf16x8*)(Vtile + (di * 16 + l15) * 64
                                           + (((c * 4 + quad) ^ sw) * 8));
                o_acc[1][di] = __builtin_amdgcn_mfma_f32_16x16x32_bf16(vf[c][di], pf1, o_acc[1][di], 0, 0, 0);
            }
        }
        __builtin_amdgcn_s_setprio(0);
        // f0 half: reuse V regs
        if (f0act) {
            SOFTMAX_P(s0, 0);
            asm volatile("s_waitcnt lgkmcnt(0)" ::: "memory");
            __builtin_amdgcn_s_setprio(1);
            #pragma unroll
            for (int c = 0; c < 2; ++c) {
                bf16x8 pf0 = *(const bf16x8*)(Pl[w] + l15 * PPAD + c * 32 + quad * 8);
                #pragma unroll
                for (int di = 0; di < 4; ++di)
                    o_acc[0][di] = __builtin_amdgcn_mfma_f32_16x16x32_bf16(vf[c][di], pf0, o_acc[0][di], 0, 0, 0);
            }
            __builtin_amdgcn_s_setprio(0);
        }
        #undef SOFTMAX_P
    }
#undef STAGE_KV

    #pragma unroll
    for (int f = 0; f < 2; ++f) {
        float lt = lrun[f];
        lt += __shfl_xor(lt, 16);
        lt += __shfl_xor(lt, 32);
        const float inv = 1.0f / lt;
        unsigned short* crow =
            CTX + (size_t)(b * TT + qb0 + f * 64 + w * 16 + l15) * CM + h * HD;
        #pragma unroll
        for (int di = 0; di < 4; ++di) {
            uint2 pk;
            pk.x = (unsigned)f32_to_bf16(o_acc[f][di][0] * inv) |
                   ((unsigned)f32_to_bf16(o_acc[f][di][1] * inv) << 16);
            pk.y = (unsigned)f32_to_bf16(o_acc[f][di][2] * inv) |
                   ((unsigned)f32_to_bf16(o_acc[f][di][3] * inv) << 16);
            *(uint2*)(crow + di * 16 + quad * 4) = pk;
        }
    }
}

// ---------------------------------------------------------------- out proj (R0-verified 128x128)
// 512 blocks at 2/CU = one perfect occupancy round (vs 256-tile's 1/CU).
__global__ __launch_bounds__(256, 2) void gemm_out(
    const unsigned short* __restrict__ CTX,
    const unsigned short* __restrict__ W,
    const float* __restrict__ bias,
    float* __restrict__ out)
{
    __shared__ __align__(16) unsigned short lds[16384];
    const int m0 = blockIdx.y * 128;
    const int n0 = blockIdx.x * 128;

    f32x4 acc[4][4];
    f32x4 z = {0.f, 0.f, 0.f, 0.f};
    #pragma unroll
    for (int mi = 0; mi < 4; ++mi)
        #pragma unroll
        for (int ni = 0; ni < 4; ++ni) acc[mi][ni] = z;

    gemm_core_dbuf<true>(CTX, W, CM, m0, n0, lds, acc);

    const int tid  = threadIdx.x;
    const int lane = tid & 63;
    const int w    = tid >> 6;
    const int wm   = (w >> 1) * 64;
    const int wn   = (w & 1) * 64;
    const int l15  = lane & 15;
    const int quad = lane >> 4;

    #pragma unroll
    for (int mi = 0; mi < 4; ++mi) {
        const int gm = m0 + wm + mi * 16 + l15;
        float* orow = out + (size_t)gm * CM;
        #pragma unroll
        for (int ni = 0; ni < 4; ++ni) {
            const int o = n0 + wn + ni * 16 + quad * 4;
            const float4 bv = *(const float4*)(bias + o);
            float4 v;
            v.x = acc[mi][ni][0] + bv.x;
            v.y = acc[mi][ni][1] + bv.y;
            v.z = acc[mi][ni][2] + bv.z;
            v.w = acc[mi][ni][3] + bv.w;
            *(float4*)(orow + o) = v;
        }
    }
}

// ---------------------------------------------------------------- launch
extern "C" void kernel_launch(void* const* d_in, const int* in_sizes, int n_in,
                              void* d_out, int out_size, void* d_ws, size_t ws_size,
                              hipStream_t stream) {
    const float* x     = (const float*)d_in[0];
    const float* qkv_w = (const float*)d_in[1];
    const float* qkv_b = (const float*)d_in[2];
    const float* out_w = (const float*)d_in[3];
    const float* out_b = (const float*)d_in[4];
    float* out = (float*)d_out;

    char* ws = (char*)d_ws;
    unsigned short* X16 = (unsigned short*)(ws + 0);         // 16 MB
    unsigned short* W1  = (unsigned short*)(ws + 16777216);  // 6 MB
    unsigned short* W2  = (unsigned short*)(ws + 23068672);  // 2 MB
    unsigned short* Qb  = (unsigned short*)(ws + 25165824);  // 16 MB
    unsigned short* Kb  = (unsigned short*)(ws + 41943040);  // 16 MB
    unsigned short* Vt  = (unsigned short*)(ws + 58720256);  // 16 MB
    unsigned short* CTX = (unsigned short*)(ws + 75497472);  // 16 MB  (~92 MB)

    cast_all<<<12288, 256, 0, stream>>>(x, qkv_w, out_w, X16, W1, W2);

    gemm_qkv<<<dim3(24, 32), 256, 0, stream>>>(X16, W1, qkv_b, Qb, Kb, Vt);
    attn_kernel<<<1024, 256, 0, stream>>>(Qb, Kb, Vt, CTX);
    gemm_out<<<dim3(8, 64), 256, 0, stream>>>(CTX, W2, out_b, out);
}